// Round 1
// baseline (2881.452 us; speedup 1.0000x reference)
//
#include <hip/hip_runtime.h>

#define T_STEPS 1024
#define BATCH   256
#define ISZ     128   // input size (layer 0)
#define HSZ     64    // hidden size
#define G4      256   // 4*H gates
#define OSZ     128   // fc output

__device__ __forceinline__ float sigmoidf_(float x) {
    return 1.0f / (1.0f + __expf(-x));
}
__device__ __forceinline__ float tanh_fast(float x) {
    // tanh(x) = 1 - 2/(exp(2x)+1); saturates correctly for |x| large
    float e = __expf(2.0f * x);
    return 1.0f - 2.0f / (e + 1.0f);
}

// ---------------- Layer 0: fused input-proj + LSTM scan -------------------
// grid = 256 (one block per batch element), block = 256 (one thread per gate)
extern "C" __global__ void __launch_bounds__(256, 1)
lstm_layer0(const float* __restrict__ x,      // [B][T][128]
            const float* __restrict__ h0,     // [B][64]  (layer-0 slice)
            const float* __restrict__ c0,     // [B][64]
            const float* __restrict__ w_ih,   // [256][128]
            const float* __restrict__ w_hh,   // [256][64]
            const float* __restrict__ b_ih,   // [256]
            const float* __restrict__ b_hh,   // [256]
            float* __restrict__ out0,         // [B][T][64]  (workspace)
            float* __restrict__ hn,           // [B][64]  (d_out slice, layer 0)
            float* __restrict__ cn)           // [B][64]
{
    const int g = threadIdx.x;   // gate index 0..255  (i: 0-63, f: 64-127, g: 128-191, o: 192-255)
    const int b = blockIdx.x;    // batch element

    __shared__ __align__(16) float xbuf[64 * ISZ];  // 32 KB: 64 timesteps of x
    __shared__ __align__(16) float gbuf[G4];        // pre-activation gates
    __shared__ __align__(16) float hbuf[HSZ];       // current hidden state

    // Per-thread weights in VGPRs (launch_bounds(256,1) -> 512-VGPR budget)
    float wih[ISZ];
    float whh[HSZ];
    {
        const float4* wr = reinterpret_cast<const float4*>(w_ih + (size_t)g * ISZ);
        #pragma unroll
        for (int k = 0; k < ISZ / 4; ++k) {
            float4 v = wr[k];
            wih[4*k+0] = v.x; wih[4*k+1] = v.y; wih[4*k+2] = v.z; wih[4*k+3] = v.w;
        }
        const float4* wr2 = reinterpret_cast<const float4*>(w_hh + (size_t)g * HSZ);
        #pragma unroll
        for (int k = 0; k < HSZ / 4; ++k) {
            float4 v = wr2[k];
            whh[4*k+0] = v.x; whh[4*k+1] = v.y; whh[4*k+2] = v.z; whh[4*k+3] = v.w;
        }
    }
    const float bias = b_ih[g] + b_hh[g];

    float c = 0.0f;
    if (g < HSZ) {
        hbuf[g] = h0[(size_t)b * HSZ + g];
        c       = c0[(size_t)b * HSZ + g];
    }
    // visibility of hbuf init is guaranteed by the chunk-load barrier at t=0

    const float4* xb4 = reinterpret_cast<const float4*>(xbuf);
    const float4* hb4 = reinterpret_cast<const float4*>(hbuf);

    for (int t = 0; t < T_STEPS; ++t) {
        const int tc = t & 63;
        if (tc == 0) {
            // stage next 64 timesteps of x (prev chunk's readers are past the
            // phase-4 barrier of step t-1, so overwrite is safe)
            const float4* src = reinterpret_cast<const float4*>(x + ((size_t)b * T_STEPS + t) * ISZ);
            float4* dst = reinterpret_cast<float4*>(xbuf);
            #pragma unroll
            for (int k = 0; k < 8; ++k) dst[g + 256 * k] = src[g + 256 * k];
            __syncthreads();
        }

        // ---- phase 1: pre-activation gate g = bias + x_t . wih[g] + h . whh[g]
        float acc4[4] = {0.f, 0.f, 0.f, 0.f};
        #pragma unroll
        for (int k = 0; k < 32; ++k) {            // x part (broadcast reads)
            float4 v = xb4[tc * 32 + k];
            float s = v.x * wih[4*k+0];
            s = fmaf(v.y, wih[4*k+1], s);
            s = fmaf(v.z, wih[4*k+2], s);
            s = fmaf(v.w, wih[4*k+3], s);
            acc4[k & 3] += s;
        }
        #pragma unroll
        for (int k = 0; k < 16; ++k) {            // h part (broadcast reads)
            float4 v = hb4[k];
            float s = v.x * whh[4*k+0];
            s = fmaf(v.y, whh[4*k+1], s);
            s = fmaf(v.z, whh[4*k+2], s);
            s = fmaf(v.w, whh[4*k+3], s);
            acc4[k & 3] += s;
        }
        gbuf[g] = bias + ((acc4[0] + acc4[1]) + (acc4[2] + acc4[3]));
        __syncthreads();

        // ---- phase 3: wave 0 applies nonlinearities, updates (c,h)
        if (g < HSZ) {
            float ig = sigmoidf_(gbuf[g]);
            float fg = sigmoidf_(gbuf[HSZ + g]);
            float gg = tanh_fast(gbuf[2 * HSZ + g]);
            float og = sigmoidf_(gbuf[3 * HSZ + g]);
            c = fg * c + ig * gg;
            float h = og * tanh_fast(c);
            hbuf[g] = h;
            out0[((size_t)b * T_STEPS + t) * HSZ + g] = h;
        }
        __syncthreads();
    }

    if (g < HSZ) {
        hn[(size_t)b * HSZ + g] = hbuf[g];
        cn[(size_t)b * HSZ + g] = c;
    }
}

// ---------- Layer 1: fused input-proj + LSTM scan + FC head ---------------
extern "C" __global__ void __launch_bounds__(256, 1)
lstm_layer1_fc(const float* __restrict__ in0,   // [B][T][64] from layer 0
               const float* __restrict__ h0,    // [B][64] (layer-1 slice)
               const float* __restrict__ c0,
               const float* __restrict__ w_ih,  // [256][64]
               const float* __restrict__ w_hh,  // [256][64]
               const float* __restrict__ b_ih,
               const float* __restrict__ b_hh,
               const float* __restrict__ w_fc,  // [128][64]
               const float* __restrict__ b_fc,  // [128]
               float* __restrict__ logits,      // [B*T][128] (d_out)
               float* __restrict__ hn,          // [B][64] (layer-1 slice)
               float* __restrict__ cn)
{
    const int g = threadIdx.x;
    const int b = blockIdx.x;

    __shared__ __align__(16) float ibuf[64 * HSZ];  // 16 KB: 64 steps of layer-0 output
    __shared__ __align__(16) float gbuf[G4];
    __shared__ __align__(16) float hbuf[HSZ];

    float wih[HSZ], whh[HSZ], wfc[HSZ];
    {
        const float4* wr = reinterpret_cast<const float4*>(w_ih + (size_t)g * HSZ);
        #pragma unroll
        for (int k = 0; k < HSZ / 4; ++k) {
            float4 v = wr[k];
            wih[4*k+0] = v.x; wih[4*k+1] = v.y; wih[4*k+2] = v.z; wih[4*k+3] = v.w;
        }
        const float4* wr2 = reinterpret_cast<const float4*>(w_hh + (size_t)g * HSZ);
        #pragma unroll
        for (int k = 0; k < HSZ / 4; ++k) {
            float4 v = wr2[k];
            whh[4*k+0] = v.x; whh[4*k+1] = v.y; whh[4*k+2] = v.z; whh[4*k+3] = v.w;
        }
        // FC weights: threads 0..127 use row g; others load row g&127 (harmless)
        const float4* wr3 = reinterpret_cast<const float4*>(w_fc + (size_t)(g & 127) * HSZ);
        #pragma unroll
        for (int k = 0; k < HSZ / 4; ++k) {
            float4 v = wr3[k];
            wfc[4*k+0] = v.x; wfc[4*k+1] = v.y; wfc[4*k+2] = v.z; wfc[4*k+3] = v.w;
        }
    }
    const float bias = b_ih[g] + b_hh[g];
    const float bfc  = b_fc[g & 127];

    float c = 0.0f;
    if (g < HSZ) {
        hbuf[g] = h0[(size_t)b * HSZ + g];
        c       = c0[(size_t)b * HSZ + g];
    }

    const float4* ib4 = reinterpret_cast<const float4*>(ibuf);
    const float4* hb4 = reinterpret_cast<const float4*>(hbuf);

    for (int t = 0; t < T_STEPS; ++t) {
        const int tc = t & 63;
        if (tc == 0) {
            const float4* src = reinterpret_cast<const float4*>(in0 + ((size_t)b * T_STEPS + t) * HSZ);
            float4* dst = reinterpret_cast<float4*>(ibuf);
            #pragma unroll
            for (int k = 0; k < 4; ++k) dst[g + 256 * k] = src[g + 256 * k];
            __syncthreads();
        }

        // ---- phase 1: gates
        float acc4[4] = {0.f, 0.f, 0.f, 0.f};
        #pragma unroll
        for (int k = 0; k < 16; ++k) {           // input (= layer-0 h) part
            float4 v = ib4[tc * 16 + k];
            float s = v.x * wih[4*k+0];
            s = fmaf(v.y, wih[4*k+1], s);
            s = fmaf(v.z, wih[4*k+2], s);
            s = fmaf(v.w, wih[4*k+3], s);
            acc4[k & 3] += s;
        }
        #pragma unroll
        for (int k = 0; k < 16; ++k) {           // recurrent part
            float4 v = hb4[k];
            float s = v.x * whh[4*k+0];
            s = fmaf(v.y, whh[4*k+1], s);
            s = fmaf(v.z, whh[4*k+2], s);
            s = fmaf(v.w, whh[4*k+3], s);
            acc4[k & 3] += s;
        }
        gbuf[g] = bias + ((acc4[0] + acc4[1]) + (acc4[2] + acc4[3]));
        __syncthreads();

        // ---- phase 3: wave 0 updates (c,h)
        if (g < HSZ) {
            float ig = sigmoidf_(gbuf[g]);
            float fg = sigmoidf_(gbuf[HSZ + g]);
            float gg = tanh_fast(gbuf[2 * HSZ + g]);
            float og = sigmoidf_(gbuf[3 * HSZ + g]);
            c = fg * c + ig * gg;
            float h = og * tanh_fast(c);
            hbuf[g] = h;
        }
        __syncthreads();

        // ---- phase 5: FC head, threads 0..127 produce logits for step t
        if (g < OSZ) {
            float f0 = 0.f, f1 = 0.f;
            #pragma unroll
            for (int k = 0; k < 16; ++k) {
                float4 v = hb4[k];
                float s = v.x * wfc[4*k+0];
                s = fmaf(v.y, wfc[4*k+1], s);
                s = fmaf(v.z, wfc[4*k+2], s);
                s = fmaf(v.w, wfc[4*k+3], s);
                if (k & 1) f1 += s; else f0 += s;
            }
            logits[((size_t)b * T_STEPS + t) * OSZ + g] = bfc + f0 + f1;
        }
        // no barrier needed here: hbuf is rewritten only after the next
        // phase-2 barrier, and gbuf writers of step t+1 don't race readers
    }

    if (g < HSZ) {
        hn[(size_t)b * HSZ + g] = hbuf[g];
        cn[(size_t)b * HSZ + g] = c;
    }
}

extern "C" void kernel_launch(void* const* d_in, const int* in_sizes, int n_in,
                              void* d_out, int out_size, void* d_ws, size_t ws_size,
                              hipStream_t stream) {
    const float* x     = (const float*)d_in[0];   // [256][1024][128]
    const float* h0    = (const float*)d_in[1];   // [2][256][64]
    const float* c0    = (const float*)d_in[2];
    const float* w_ih0 = (const float*)d_in[3];
    const float* w_hh0 = (const float*)d_in[4];
    const float* b_ih0 = (const float*)d_in[5];
    const float* b_hh0 = (const float*)d_in[6];
    const float* w_ih1 = (const float*)d_in[7];
    const float* w_hh1 = (const float*)d_in[8];
    const float* b_ih1 = (const float*)d_in[9];
    const float* b_hh1 = (const float*)d_in[10];
    const float* w_fc  = (const float*)d_in[11];
    const float* b_fc  = (const float*)d_in[12];

    float* out = (float*)d_out;
    const size_t n_logits = (size_t)BATCH * T_STEPS * OSZ;   // 33,554,432
    const size_t n_state  = (size_t)BATCH * HSZ;             // 16,384 per layer
    float* logits = out;
    float* hn     = out + n_logits;            // [2][256][64]
    float* cn     = hn + 2 * n_state;          // [2][256][64]

    float* out0 = (float*)d_ws;                // [256][1024][64] = 64 MB scratch

    lstm_layer0<<<BATCH, 256, 0, stream>>>(
        x, h0, c0, w_ih0, w_hh0, b_ih0, b_hh0,
        out0, hn, cn);

    lstm_layer1_fc<<<BATCH, 256, 0, stream>>>(
        out0, h0 + n_state, c0 + n_state,
        w_ih1, w_hh1, b_ih1, b_hh1, w_fc, b_fc,
        logits, hn + n_state, cn + n_state);
}

// Round 5
// 1816.803 us; speedup vs baseline: 1.5860x; 1.5860x over previous
//
#include <hip/hip_runtime.h>

#define T_STEPS 1024
#define BATCH   256
#define HSZ     64
#define OSZ     128

__device__ __forceinline__ float fast_rcp(float x) { return __builtin_amdgcn_rcpf(x); }
__device__ __forceinline__ float tanhf_(float x) {
    // tanh(x) = 1 - 2/(exp(2x)+1)
    float e = __expf(2.0f * x);
    return fmaf(-2.0f, fast_rcp(e + 1.0f), 1.0f);
}

// Thread layout (512 threads): j = t>>3 (hidden unit), gt = (t>>1)&3 (gate i,f,g,o), hf = t&1 (dot half).
// All 8 lanes of a hidden-unit group are contiguous in one wave -> shfl_xor(1/2/4) stays in-group.

// ---------------- Layer 0: x[128] input, fused scan -------------------
extern "C" __global__ void __launch_bounds__(512, 2)
lstm_l0(const float* __restrict__ x,      // [B][T][128]
        const float* __restrict__ h0,     // [B][64]
        const float* __restrict__ c0,     // [B][64]
        const float* __restrict__ w_ih,   // [256][128]
        const float* __restrict__ w_hh,   // [256][64]
        const float* __restrict__ b_ih,   // [256]
        const float* __restrict__ b_hh,   // [256]
        float* __restrict__ out0,         // [B][T][64] (ws)
        float* __restrict__ hn, float* __restrict__ cn)
{
    const int t_ = threadIdx.x;
    const int b  = blockIdx.x;
    const int j  = t_ >> 3;
    const int gt = (t_ >> 1) & 3;
    const int hf = t_ & 1;
    const int row = gt * HSZ + j;

    __shared__ __align__(16) float xbuf[64 * 128];   // 32 KB chunk of x
    __shared__ __align__(16) float obuf[64 * HSZ];   // 16 KB staged h outputs
    __shared__ __align__(16) float hbuf[2][HSZ];     // double-buffered hidden state

    float wih[64], whh[32];
    {
        const float4* wr = reinterpret_cast<const float4*>(w_ih + (size_t)row * 128 + hf * 64);
        #pragma unroll
        for (int k = 0; k < 16; ++k) { float4 v = wr[k];
            wih[4*k+0]=v.x; wih[4*k+1]=v.y; wih[4*k+2]=v.z; wih[4*k+3]=v.w; }
        const float4* wr2 = reinterpret_cast<const float4*>(w_hh + (size_t)row * 64 + hf * 32);
        #pragma unroll
        for (int k = 0; k < 8; ++k) { float4 v = wr2[k];
            whh[4*k+0]=v.x; whh[4*k+1]=v.y; whh[4*k+2]=v.z; whh[4*k+3]=v.w; }
    }
    const float bias = b_ih[row] + b_hh[row];
    const float am = (gt == 2) ? -2.0f : -1.0f;   // exp scale
    const float aa = (gt == 2) ?  2.0f :  1.0f;   // act = aa*r + ab
    const float ab = (gt == 2) ? -1.0f :  0.0f;

    float c = c0[(size_t)b * HSZ + j];            // replicated across 8 lanes
    float h = 0.0f;
    if ((t_ & 7) == 0) hbuf[0][j] = h0[(size_t)b * HSZ + j];
    // visibility via the t=0 staging barrier

    for (int t = 0; t < T_STEPS; ++t) {
        const int tc = t & 63;
        const int p  = t & 1;
        if (tc == 0) {
            if (t) {  // flush previous 64 steps of h (coalesced)
                float4* dst = reinterpret_cast<float4*>(out0 + ((size_t)b * T_STEPS + (t - 64)) * HSZ);
                const float4* s4 = reinterpret_cast<const float4*>(obuf);
                #pragma unroll
                for (int k = 0; k < 2; ++k) dst[t_ + 512 * k] = s4[t_ + 512 * k];
            }
            const float4* src = reinterpret_cast<const float4*>(x + ((size_t)b * T_STEPS + t) * 128);
            float4* dxt = reinterpret_cast<float4*>(xbuf);
            #pragma unroll
            for (int k = 0; k < 4; ++k) dxt[t_ + 512 * k] = src[t_ + 512 * k];
            __syncthreads();
        }

        // half gate dot: 64 x-FMAs + 32 h-FMAs
        const float4* xv = reinterpret_cast<const float4*>(xbuf + tc * 128 + hf * 64);
        const float4* hv = reinterpret_cast<const float4*>(&hbuf[p][hf * 32]);
        float a0 = 0.f, a1 = 0.f, a2 = 0.f, a3 = 0.f;
        #pragma unroll
        for (int k = 0; k < 16; ++k) { float4 v = xv[k];
            a0 = fmaf(v.x, wih[4*k+0], a0);
            a1 = fmaf(v.y, wih[4*k+1], a1);
            a2 = fmaf(v.z, wih[4*k+2], a2);
            a3 = fmaf(v.w, wih[4*k+3], a3); }
        #pragma unroll
        for (int k = 0; k < 8; ++k) { float4 v = hv[k];
            a0 = fmaf(v.x, whh[4*k+0], a0);
            a1 = fmaf(v.y, whh[4*k+1], a1);
            a2 = fmaf(v.z, whh[4*k+2], a2);
            a3 = fmaf(v.w, whh[4*k+3], a3); }
        float part = (a0 + a1) + (a2 + a3);
        float pre  = part + __shfl_xor(part, 1) + bias;

        // parallel activation (sigmoid or tanh, branchless)
        float act = fmaf(aa, fast_rcp(1.0f + __expf(am * pre)), ab);

        // gather the 4 gates of hidden unit j (in-wave butterfly)
        float q1 = __shfl_xor(act, 2);   // gate gt^1
        float q2 = __shfl_xor(act, 4);   // gate gt^2
        float q3 = __shfl_xor(q1, 4);    // gate gt^3
        const bool b0 = (gt & 1), b1 = (gt & 2);
        float lo  = b0 ? q1  : act;
        float hi  = b0 ? q3  : q2;
        float lo2 = b0 ? act : q1;
        float hi2 = b0 ? q2  : q3;
        float iv = b1 ? hi  : lo;    // gate 0 (i)
        float fv = b1 ? hi2 : lo2;   // gate 1 (f)
        float gv = b1 ? lo  : hi;    // gate 2 (g)
        float ov = b1 ? lo2 : hi2;   // gate 3 (o)

        c = fmaf(fv, c, iv * gv);    // replicated update, no divergence
        h = ov * tanhf_(c);
        if ((t_ & 7) == 0) { hbuf[p ^ 1][j] = h; obuf[tc * HSZ + j] = h; }
        __syncthreads();
    }

    {   // final chunk flush
        float4* dst = reinterpret_cast<float4*>(out0 + ((size_t)b * T_STEPS + (T_STEPS - 64)) * HSZ);
        const float4* s4 = reinterpret_cast<const float4*>(obuf);
        #pragma unroll
        for (int k = 0; k < 2; ++k) dst[t_ + 512 * k] = s4[t_ + 512 * k];
    }
    if ((t_ & 7) == 0) {
        hn[(size_t)b * HSZ + j] = h;
        cn[(size_t)b * HSZ + j] = c;
    }
}

// ---------------- Layer 1 (+ fused FC head) -------------------
extern "C" __global__ void __launch_bounds__(512, 2)
lstm_l1_fc(const float* __restrict__ in0,   // [B][T][64]
           const float* __restrict__ h0, const float* __restrict__ c0,
           const float* __restrict__ w_ih,  // [256][64]
           const float* __restrict__ w_hh,  // [256][64]
           const float* __restrict__ b_ih, const float* __restrict__ b_hh,
           const float* __restrict__ w_fc,  // [128][64]
           const float* __restrict__ b_fc,  // [128]
           float* __restrict__ logits,      // [B*T][128]
           float* __restrict__ hn, float* __restrict__ cn)
{
    const int t_ = threadIdx.x;
    const int b  = blockIdx.x;
    const int j  = t_ >> 3;
    const int gt = (t_ >> 1) & 3;
    const int hf = t_ & 1;
    const int row = gt * HSZ + j;
    const int o  = t_ >> 2;          // FC output 0..127
    const int q  = t_ & 3;           // FC quarter

    __shared__ __align__(16) float ibuf[64 * HSZ];    // 16 KB chunk of layer-0 h
    __shared__ __align__(16) float lbuf[64 * OSZ];    // 32 KB staged logits
    __shared__ __align__(16) float hbuf[2][HSZ];

    float wih[32], whh[32], wfc[16];
    {
        const float4* wr = reinterpret_cast<const float4*>(w_ih + (size_t)row * 64 + hf * 32);
        #pragma unroll
        for (int k = 0; k < 8; ++k) { float4 v = wr[k];
            wih[4*k+0]=v.x; wih[4*k+1]=v.y; wih[4*k+2]=v.z; wih[4*k+3]=v.w; }
        const float4* wr2 = reinterpret_cast<const float4*>(w_hh + (size_t)row * 64 + hf * 32);
        #pragma unroll
        for (int k = 0; k < 8; ++k) { float4 v = wr2[k];
            whh[4*k+0]=v.x; whh[4*k+1]=v.y; whh[4*k+2]=v.z; whh[4*k+3]=v.w; }
        const float4* wr3 = reinterpret_cast<const float4*>(w_fc + (size_t)o * 64 + q * 16);
        #pragma unroll
        for (int k = 0; k < 4; ++k) { float4 v = wr3[k];
            wfc[4*k+0]=v.x; wfc[4*k+1]=v.y; wfc[4*k+2]=v.z; wfc[4*k+3]=v.w; }
    }
    const float bias = b_ih[row] + b_hh[row];
    const float bfc  = b_fc[o];
    const float am = (gt == 2) ? -2.0f : -1.0f;
    const float aa = (gt == 2) ?  2.0f :  1.0f;
    const float ab = (gt == 2) ? -1.0f :  0.0f;

    float c = c0[(size_t)b * HSZ + j];
    float h = 0.0f;
    if ((t_ & 7) == 0) hbuf[0][j] = h0[(size_t)b * HSZ + j];

    for (int t = 0; t < T_STEPS; ++t) {
        const int tc = t & 63;
        const int p  = t & 1;

        // FC head for step t-1 (h_{t-1} lives in hbuf[p])
        if (t) {
            float f0 = 0.f;
            const float4* hv4 = reinterpret_cast<const float4*>(&hbuf[p][q * 16]);
            #pragma unroll
            for (int k = 0; k < 4; ++k) { float4 v = hv4[k];
                f0 = fmaf(v.x, wfc[4*k+0], f0);
                f0 = fmaf(v.y, wfc[4*k+1], f0);
                f0 = fmaf(v.z, wfc[4*k+2], f0);
                f0 = fmaf(v.w, wfc[4*k+3], f0); }
            f0 += __shfl_xor(f0, 1);
            f0 += __shfl_xor(f0, 2);
            int slot = (tc == 0) ? 63 : (tc - 1);
            if (q == 0) lbuf[slot * OSZ + o] = f0 + bfc;
        }

        if (tc == 0) {
            if (t) {
                __syncthreads();   // lbuf[63] visible to flushers
                float4* dst = reinterpret_cast<float4*>(logits + ((size_t)b * T_STEPS + (t - 64)) * OSZ);
                const float4* s4 = reinterpret_cast<const float4*>(lbuf);
                #pragma unroll
                for (int k = 0; k < 4; ++k) dst[t_ + 512 * k] = s4[t_ + 512 * k];
            }
            const float4* src = reinterpret_cast<const float4*>(in0 + ((size_t)b * T_STEPS + t) * HSZ);
            float4* dxt = reinterpret_cast<float4*>(ibuf);
            #pragma unroll
            for (int k = 0; k < 2; ++k) dxt[t_ + 512 * k] = src[t_ + 512 * k];
            __syncthreads();
        }

        // gates: 32 input-FMAs + 32 h-FMAs per thread
        const float4* xv = reinterpret_cast<const float4*>(ibuf + tc * HSZ + hf * 32);
        const float4* hv = reinterpret_cast<const float4*>(&hbuf[p][hf * 32]);
        float a0 = 0.f, a1 = 0.f, a2 = 0.f, a3 = 0.f;
        #pragma unroll
        for (int k = 0; k < 8; ++k) { float4 v = xv[k];
            a0 = fmaf(v.x, wih[4*k+0], a0);
            a1 = fmaf(v.y, wih[4*k+1], a1);
            a2 = fmaf(v.z, wih[4*k+2], a2);
            a3 = fmaf(v.w, wih[4*k+3], a3); }
        #pragma unroll
        for (int k = 0; k < 8; ++k) { float4 v = hv[k];
            a0 = fmaf(v.x, whh[4*k+0], a0);
            a1 = fmaf(v.y, whh[4*k+1], a1);
            a2 = fmaf(v.z, whh[4*k+2], a2);
            a3 = fmaf(v.w, whh[4*k+3], a3); }
        float part = (a0 + a1) + (a2 + a3);
        float pre  = part + __shfl_xor(part, 1) + bias;

        float act = fmaf(aa, fast_rcp(1.0f + __expf(am * pre)), ab);
        float q1 = __shfl_xor(act, 2);
        float q2 = __shfl_xor(act, 4);
        float q3 = __shfl_xor(q1, 4);
        const bool b0 = (gt & 1), b1 = (gt & 2);
        float lo  = b0 ? q1  : act;
        float hi  = b0 ? q3  : q2;
        float lo2 = b0 ? act : q1;
        float hi2 = b0 ? q2  : q3;
        float iv = b1 ? hi  : lo;
        float fv = b1 ? hi2 : lo2;
        float gv = b1 ? lo  : hi;
        float ov = b1 ? lo2 : hi2;

        c = fmaf(fv, c, iv * gv);
        h = ov * tanhf_(c);
        if ((t_ & 7) == 0) hbuf[p ^ 1][j] = h;
        __syncthreads();
    }

    {   // final FC (t = 1023; h_1023 in hbuf[0]) + last flush
        float f0 = 0.f;
        const float4* hv4 = reinterpret_cast<const float4*>(&hbuf[0][q * 16]);
        #pragma unroll
        for (int k = 0; k < 4; ++k) { float4 v = hv4[k];
            f0 = fmaf(v.x, wfc[4*k+0], f0);
            f0 = fmaf(v.y, wfc[4*k+1], f0);
            f0 = fmaf(v.z, wfc[4*k+2], f0);
            f0 = fmaf(v.w, wfc[4*k+3], f0); }
        f0 += __shfl_xor(f0, 1);
        f0 += __shfl_xor(f0, 2);
        if (q == 0) lbuf[63 * OSZ + o] = f0 + bfc;
        __syncthreads();
        float4* dst = reinterpret_cast<float4*>(logits + ((size_t)b * T_STEPS + (T_STEPS - 64)) * OSZ);
        const float4* s4 = reinterpret_cast<const float4*>(lbuf);
        #pragma unroll
        for (int k = 0; k < 4; ++k) dst[t_ + 512 * k] = s4[t_ + 512 * k];
    }
    if ((t_ & 7) == 0) {
        hn[(size_t)b * HSZ + j] = h;
        cn[(size_t)b * HSZ + j] = c;
    }
}

extern "C" void kernel_launch(void* const* d_in, const int* in_sizes, int n_in,
                              void* d_out, int out_size, void* d_ws, size_t ws_size,
                              hipStream_t stream) {
    const float* x     = (const float*)d_in[0];
    const float* h0    = (const float*)d_in[1];
    const float* c0    = (const float*)d_in[2];
    const float* w_ih0 = (const float*)d_in[3];
    const float* w_hh0 = (const float*)d_in[4];
    const float* b_ih0 = (const float*)d_in[5];
    const float* b_hh0 = (const float*)d_in[6];
    const float* w_ih1 = (const float*)d_in[7];
    const float* w_hh1 = (const float*)d_in[8];
    const float* b_ih1 = (const float*)d_in[9];
    const float* b_hh1 = (const float*)d_in[10];
    const float* w_fc  = (const float*)d_in[11];
    const float* b_fc  = (const float*)d_in[12];

    float* out = (float*)d_out;
    const size_t n_logits = (size_t)BATCH * T_STEPS * OSZ;
    const size_t n_state  = (size_t)BATCH * HSZ;
    float* logits = out;
    float* hn     = out + n_logits;
    float* cn     = hn + 2 * n_state;

    float* out0 = (float*)d_ws;   // [256][1024][64]

    lstm_l0<<<BATCH, 512, 0, stream>>>(
        x, h0, c0, w_ih0, w_hh0, b_ih0, b_hh0, out0, hn, cn);

    lstm_l1_fc<<<BATCH, 512, 0, stream>>>(
        out0, h0 + n_state, c0 + n_state,
        w_ih1, w_hh1, b_ih1, b_hh1, w_fc, b_fc,
        logits, hn + n_state, cn + n_state);
}